// Round 1
// baseline (1789.597 us; speedup 1.0000x reference)
//
#include <hip/hip_runtime.h>
#include <hip/hip_bf16.h>
#include <math.h>

// Problem constants (fixed by setup_inputs): B=256 graphs, N=256 nodes/graph,
// DEG=8, D=128, L=3 layers. E = 524288 edges (2048 per graph, graph-contiguous).
#define DD     128
#define NGRAPH 256
#define ECAPG  2048
#define ETOT   (NGRAPH*ECAPG)
#define NMAX   65536

struct Heads {
  const float* W[4];
  const float* b[4];
  float*       O[4];
};

// ---- pool_w inverse norms (3 scalars) ----
__global__ __launch_bounds__(128) void k_wnorm(const float* pw, float* wni){
  int l = blockIdx.x, t = threadIdx.x;
  __shared__ float s[128];
  float v = pw[l*DD + t];
  s[t] = v*v; __syncthreads();
  for (int o=64;o>0;o>>=1){ if (t<o) s[t]+=s[t+o]; __syncthreads(); }
  if (t==0) wni[l] = 1.0f/sqrtf(s[0]);
}

__global__ __launch_bounds__(256) void k_init_ecnt(int* e0){ e0[threadIdx.x] = ECAPG; }

// ---- CSR build: count / scan / scatter (edges grouped per graph at base g*ECAPG) ----
__global__ __launch_bounds__(256) void k_count(const int* dst, const int* ecnt, int* counts){
  int idx = blockIdx.x*256 + threadIdx.x;
  int g = idx >> 11, e = idx & (ECAPG-1);
  if (e < ecnt[g]) atomicAdd(&counts[dst[idx]], 1);
}

__global__ __launch_bounds__(256) void k_scan(const int* counts, int* row_start, int* cursor, int n){
  int g = blockIdx.x, t = threadIdx.x;
  __shared__ int sh[256];
  int c = (t<n) ? counts[g*n+t] : 0;
  sh[t] = c; __syncthreads();
  for (int o=1;o<256;o<<=1){
    int add = (t>=o) ? sh[t-o] : 0;
    __syncthreads();
    sh[t] += add;
    __syncthreads();
  }
  if (t<n){ int rs = g*ECAPG + sh[t]-c; row_start[g*n+t]=rs; cursor[g*n+t]=rs; }
}

__global__ __launch_bounds__(256) void k_scatter(const int* src, const int* dst, const int* ecnt,
                                                 int* cursor, int* ssrc){
  int idx = blockIdx.x*256 + threadIdx.x;
  int g = idx >> 11, e = idx & (ECAPG-1);
  if (e < ecnt[g]){ int p = atomicAdd(&cursor[dst[idx]],1); ssrc[p] = src[idx]; }
}

// ---- fp32 GEMM: OUT = act(X @ W + b), tile 64 rows x 64 cols, K=128 split in two ----
__global__ __launch_bounds__(256,3) void k_gemm(const float* __restrict__ X, Heads h, int relu){
  int rowTile = blockIdx.x, colChunk = blockIdx.y, head = blockIdx.z;
  const float* W = h.W[head]; const float* bias = h.b[head]; float* O = h.O[head];
  __shared__ float Xs[64][132];
  __shared__ float Ws[64][64];
  int t = threadIdx.x;
  const float* Xb = X + (size_t)rowTile*64*DD;
  int tr = t >> 4, tc = t & 15;
  int r0 = tr*4, c0 = tc*4;
  float acc[4][4] = {};
  for (int i=t; i<64*32; i+=256){
    int r = i>>5, q4 = i&31;
    *(float4*)&Xs[r][q4*4] = *(const float4*)(Xb + r*DD + q4*4);
  }
  for (int kh=0; kh<2; kh++){
    __syncthreads();
    for (int i=t; i<64*16; i+=256){
      int r = i>>4, q4 = i&15;
      *(float4*)&Ws[r][q4*4] = *(const float4*)(W + (size_t)(kh*64+r)*DD + colChunk*64 + q4*4);
    }
    __syncthreads();
    for (int kk=0; kk<64; kk+=4){
      float4 xv[4], wv[4];
      #pragma unroll
      for (int i=0;i<4;i++) xv[i] = *(const float4*)&Xs[r0+i][kh*64+kk];
      #pragma unroll
      for (int j=0;j<4;j++) wv[j] = *(const float4*)&Ws[kk+j][c0];
      #pragma unroll
      for (int i=0;i<4;i++){
        acc[i][0] += xv[i].x*wv[0].x + xv[i].y*wv[1].x + xv[i].z*wv[2].x + xv[i].w*wv[3].x;
        acc[i][1] += xv[i].x*wv[0].y + xv[i].y*wv[1].y + xv[i].z*wv[2].y + xv[i].w*wv[3].y;
        acc[i][2] += xv[i].x*wv[0].z + xv[i].y*wv[1].z + xv[i].z*wv[2].z + xv[i].w*wv[3].z;
        acc[i][3] += xv[i].x*wv[0].w + xv[i].y*wv[1].w + xv[i].z*wv[2].w + xv[i].w*wv[3].w;
      }
    }
  }
  int cbase = colChunk*64 + c0;
  float4 bv = *(const float4*)(bias + cbase);
  #pragma unroll
  for (int i=0;i<4;i++){
    float4 o;
    o.x = acc[i][0]+bv.x; o.y = acc[i][1]+bv.y; o.z = acc[i][2]+bv.z; o.w = acc[i][3]+bv.w;
    if (relu){ o.x=fmaxf(o.x,0.f); o.y=fmaxf(o.y,0.f); o.z=fmaxf(o.z,0.f); o.w=fmaxf(o.w,0.f); }
    *(float4*)(O + (size_t)(rowTile*64 + r0 + i)*DD + cbase) = o;
  }
}

// ---- attention: one wave per dst node, CSR edges, softmax over incoming edges ----
__global__ __launch_bounds__(256) void k_attn(const float* __restrict__ q, const float* __restrict__ k,
                                              const float* __restrict__ v,
                                              const int* row_start, const int* row_end,
                                              const int* ssrc, float* xat){
  int w = threadIdx.x >> 6, lane = threadIdx.x & 63;
  int node = blockIdx.x*4 + w;
  __shared__ float lg[4][128];
  const float isd = 0.088388347648318447f; // 1/sqrt(128)
  float2 qv = *(const float2*)(q + (size_t)node*DD + lane*2);
  int s0 = row_start[node], s1 = row_end[node];
  int deg = s1 - s0; if (deg > 128) deg = 128;
  for (int j=0;j<deg;j++){
    int s = ssrc[s0+j];
    float2 kv = *(const float2*)(k + (size_t)s*DD + lane*2);
    float p = qv.x*kv.x + qv.y*kv.y;
    #pragma unroll
    for (int o=32;o>0;o>>=1) p += __shfl_xor(p, o, 64);
    if (lane==0) lg[w][j] = p * isd;
  }
  __syncthreads();
  float acc0=0.f, acc1=0.f;
  if (deg > 0){
    float m = -1e30f;
    for (int j=0;j<deg;j++) m = fmaxf(m, lg[w][j]);
    float denom = 0.f;
    for (int j=0;j<deg;j++) denom += expf(lg[w][j]-m);
    float rd = 1.0f/denom;
    for (int j=0;j<deg;j++){
      int s = ssrc[s0+j];
      float a = expf(lg[w][j]-m)*rd;
      float2 vv = *(const float2*)(v + (size_t)s*DD + lane*2);
      acc0 += a*vv.x; acc1 += a*vv.y;
    }
  }
  float2 xo = *(const float2*)(xat + (size_t)node*DD + lane*2);
  xo.x += acc0; xo.y += acc1;
  *(float2*)(xat + (size_t)node*DD + lane*2) = xo;
}

// ---- batchnorm stats (deterministic two-stage) ----
__global__ __launch_bounds__(256) void k_bnpart(const float* __restrict__ h, float* psum, float* psq, int rpb){
  int c = threadIdx.x & 127, half = threadIdx.x >> 7;
  size_t base = (size_t)blockIdx.x * rpb;
  float s=0.f, s2=0.f;
  for (int r=half; r<rpb; r+=2){
    float x = h[(base+r)*DD + c];
    s += x; s2 += x*x;
  }
  __shared__ float sh[256], sh2[256];
  sh[threadIdx.x]=s; sh2[threadIdx.x]=s2;
  __syncthreads();
  if (half==0){
    psum[blockIdx.x*DD + c] = s + sh[threadIdx.x+128];
    psq [blockIdx.x*DD + c] = s2 + sh2[threadIdx.x+128];
  }
}

__global__ __launch_bounds__(128) void k_bnfin(const float* psum, const float* psq,
                                               float* mu, float* istd, float invN){
  int c = threadIdx.x;
  float s=0.f, s2=0.f;
  for (int b2=0;b2<128;b2++){ s += psum[b2*DD+c]; s2 += psq[b2*DD+c]; }
  float m = s*invN;
  float var = fmaxf(s2*invN - m*m, 0.f);
  mu[c]=m; istd[c] = 1.0f/sqrtf(var + 1e-5f);
}

// ---- BN-normalize + write xbn + pooling score ----
__global__ __launch_bounds__(256) void k_score(const float* __restrict__ h, const float* mu, const float* istd,
                                               const float* gamma, const float* beta,
                                               const float* pw, const float* wni,
                                               float* xbn, float* score){
  int w = threadIdx.x>>6, lane = threadIdx.x&63;
  int node = blockIdx.x*4 + w;
  int d0 = lane*2;
  float2 hv = *(const float2*)(h + (size_t)node*DD + d0);
  float x0 = (hv.x - mu[d0  ])*istd[d0  ]*gamma[d0  ] + beta[d0  ];
  float x1 = (hv.y - mu[d0+1])*istd[d0+1]*gamma[d0+1] + beta[d0+1];
  *(float2*)(xbn + (size_t)node*DD + d0) = make_float2(x0,x1);
  float p = x0*pw[d0] + x1*pw[d0+1];
  #pragma unroll
  for (int o=32;o>0;o>>=1) p += __shfl_xor(p, o, 64);
  if (lane==0) score[node] = tanhf(p * wni[0]);
}

// ---- per-graph top-k via exact ranking (matches jax.lax.top_k incl. tie order) ----
__global__ __launch_bounds__(256) void k_topk(const float* score, int n, int kk,
                                              int* sel, float* skeep, int* newid){
  int g = blockIdx.x, t = threadIdx.x;
  __shared__ float ss[256];
  if (t<n) ss[t] = score[g*n+t];
  __syncthreads();
  if (t>=n) return;
  float si = ss[t];
  int rank = 0;
  for (int j=0;j<n;j++){
    float sj = ss[j];
    rank += (sj > si) || ((sj == si) && (j < t));
  }
  if (rank < kk){
    sel[g*kk+rank] = g*n+t;
    skeep[g*kk+rank] = si;
    newid[g*n+t] = g*kk + rank;
  } else {
    newid[g*n+t] = -1;
  }
}

__global__ __launch_bounds__(256) void k_gather(const float* __restrict__ xbn, const int* sel,
                                                const float* skeep, float* xn){
  int w = threadIdx.x>>6, lane = threadIdx.x&63;
  int p = blockIdx.x*4 + w;
  int srow = sel[p]; float sc = skeep[p];
  float2 xv = *(const float2*)(xbn + (size_t)srow*DD + lane*2);
  xv.x *= sc; xv.y *= sc;
  *(float2*)(xn + (size_t)p*DD + lane*2) = xv;
}

__global__ __launch_bounds__(128) void k_readout(const float* __restrict__ xn, float* out, int kk, int layer){
  int g = blockIdx.x, c = threadIdx.x;
  float mx = -1e30f, sm = 0.f;
  for (int nd=0; nd<kk; nd++){
    float x = xn[((size_t)g*kk + nd)*DD + c];
    mx = fmaxf(mx, x); sm += x;
  }
  float* ob = out + (size_t)g*(3*3*DD) + layer*3*DD;
  ob[c] = mx; ob[DD+c] = sm/(float)kk; ob[2*DD+c] = sm;
}

// ---- edge remap + compaction for next layer ----
__global__ __launch_bounds__(256) void k_remap(const int* src, const int* dst, const int* ecnt,
                                               const int* newid, int* nsrc, int* ndst, int* necnt){
  int idx = blockIdx.x*256 + threadIdx.x;
  int g = idx>>11, e = idx&(ECAPG-1);
  if (e < ecnt[g]){
    int ns = newid[src[idx]], nd = newid[dst[idx]];
    if ((ns|nd) >= 0){
      int p = atomicAdd(&necnt[g], 1);
      nsrc[g*ECAPG+p] = ns; ndst[g*ECAPG+p] = nd;
    }
  }
}

extern "C" void kernel_launch(void* const* d_in, const int* in_sizes, int n_in,
                              void* d_out, int out_size, void* d_ws, size_t ws_size,
                              hipStream_t stream){
  const float* x0   = (const float*)d_in[0];
  const int*   eidx = (const int*)d_in[1];
  const float* Wq = (const float*)d_in[4];  const float* bq = (const float*)d_in[5];
  const float* Wk = (const float*)d_in[6];  const float* bk = (const float*)d_in[7];
  const float* Wv = (const float*)d_in[8];  const float* bv = (const float*)d_in[9];
  const float* Wsk= (const float*)d_in[10]; const float* bsk= (const float*)d_in[11];
  const float* Wt = (const float*)d_in[12]; const float* bt = (const float*)d_in[13];
  const float* gamma = (const float*)d_in[14]; const float* beta = (const float*)d_in[15];
  const float* pw = (const float*)d_in[16];

  char* w8 = (char*)d_ws;
  size_t off = 0;
  auto alloc = [&](size_t bytes)->void*{ void* p = w8+off; off += (bytes+255)&~(size_t)255; return p; };

  float* qb  = (float*)alloc((size_t)NMAX*DD*4);
  float* kb  = (float*)alloc((size_t)NMAX*DD*4);
  float* vb  = (float*)alloc((size_t)NMAX*DD*4);
  float* xsb = (float*)alloc((size_t)NMAX*DD*4);
  float* xb0 = (float*)alloc((size_t)(NMAX/2)*DD*4);
  float* xb1 = (float*)alloc((size_t)(NMAX/2)*DD*4);
  float* scores = (float*)alloc(NMAX*4);
  float* skeep  = (float*)alloc((NMAX/2)*4);
  float* psum = (float*)alloc(128*DD*4);
  float* psq  = (float*)alloc(128*DD*4);
  float* mu   = (float*)alloc(DD*4);
  float* istd = (float*)alloc(DD*4);
  float* wni  = (float*)alloc(64);
  int* counts    = (int*)alloc(NMAX*4);
  int* row_start = (int*)alloc(NMAX*4);
  int* cursor    = (int*)alloc(NMAX*4);
  int* ssrc      = (int*)alloc(ETOT*4);
  int* srcA = (int*)alloc(ETOT*4);
  int* dstA = (int*)alloc(ETOT*4);
  int* srcB = (int*)alloc(ETOT*4);
  int* dstB = (int*)alloc(ETOT*4);
  int* sel   = (int*)alloc((NMAX/2)*4);
  int* newid = (int*)alloc(NMAX*4);
  int* ecnt0 = (int*)alloc(NGRAPH*4);
  int* ecntA = (int*)alloc(NGRAPH*4);
  int* ecntB = (int*)alloc(NGRAPH*4);

  k_wnorm<<<3,128,0,stream>>>(pw, wni);
  k_init_ecnt<<<1,256,0,stream>>>(ecnt0);

  const float* xcur = x0;
  const int* csrc = eidx;
  const int* cdst = eidx + ETOT;
  const int* cecnt = ecnt0;
  int n = 256;

  for (int layer=0; layer<3; layer++){
    int Nn = NGRAPH * n;
    int kk = n/2;

    hipMemsetAsync(counts, 0, (size_t)Nn*4, stream);
    k_count  <<<ETOT/256,256,0,stream>>>(cdst, cecnt, counts);
    k_scan   <<<NGRAPH,256,0,stream>>>(counts, row_start, cursor, n);
    k_scatter<<<ETOT/256,256,0,stream>>>(csrc, cdst, cecnt, cursor, ssrc);

    Heads h4;
    h4.W[0]=Wq +(size_t)layer*DD*DD; h4.b[0]=bq +layer*DD; h4.O[0]=qb;
    h4.W[1]=Wk +(size_t)layer*DD*DD; h4.b[1]=bk +layer*DD; h4.O[1]=kb;
    h4.W[2]=Wv +(size_t)layer*DD*DD; h4.b[2]=bv +layer*DD; h4.O[2]=vb;
    h4.W[3]=Wsk+(size_t)layer*DD*DD; h4.b[3]=bsk+layer*DD; h4.O[3]=xsb;
    k_gemm<<<dim3(Nn/64,2,4),256,0,stream>>>(xcur, h4, 0);

    k_attn<<<Nn/4,256,0,stream>>>(qb, kb, vb, row_start, cursor, ssrc, xsb);

    Heads h1;
    h1.W[0]=Wt+(size_t)layer*DD*DD; h1.b[0]=bt+layer*DD; h1.O[0]=qb;
    h1.W[1]=h1.W[0]; h1.b[1]=h1.b[0]; h1.O[1]=qb;
    h1.W[2]=h1.W[0]; h1.b[2]=h1.b[0]; h1.O[2]=qb;
    h1.W[3]=h1.W[0]; h1.b[3]=h1.b[0]; h1.O[3]=qb;
    k_gemm<<<dim3(Nn/64,2,1),256,0,stream>>>(xsb, h1, 1);

    k_bnpart<<<128,256,0,stream>>>(qb, psum, psq, Nn/128);
    k_bnfin <<<1,128,0,stream>>>(psum, psq, mu, istd, 1.0f/(float)Nn);

    k_score<<<Nn/4,256,0,stream>>>(qb, mu, istd, gamma+layer*DD, beta+layer*DD,
                                   pw+layer*DD, wni+layer, kb, scores);

    k_topk<<<NGRAPH,256,0,stream>>>(scores, n, kk, sel, skeep, newid);

    float* xn = (layer==0) ? xb0 : ((layer==1) ? xb1 : xb0);
    k_gather<<<(NGRAPH*kk)/4,256,0,stream>>>(kb, sel, skeep, xn);
    k_readout<<<NGRAPH,128,0,stream>>>(xn, (float*)d_out, kk, layer);

    if (layer<2){
      int* nsrc  = (layer==0) ? srcA : srcB;
      int* ndst  = (layer==0) ? dstA : dstB;
      int* necnt = (layer==0) ? ecntA : ecntB;
      hipMemsetAsync(necnt, 0, NGRAPH*4, stream);
      k_remap<<<ETOT/256,256,0,stream>>>(csrc, cdst, cecnt, newid, nsrc, ndst, necnt);
      csrc = nsrc; cdst = ndst; cecnt = necnt;
    }
    xcur = xn; n = kk;
  }
}

// Round 2
// 703.439 us; speedup vs baseline: 2.5441x; 2.5441x over previous
//
#include <hip/hip_runtime.h>
#include <hip/hip_bf16.h>
#include <math.h>

// B=256 graphs, N=256 nodes/graph, DEG=8, D=128, L=3.
#define DD     128
#define NGRAPH 256
#define ECAPG  2048
#define ETOT   (NGRAPH*ECAPG)
#define NMAX   65536

typedef __attribute__((ext_vector_type(8))) short bf16x8;
typedef __attribute__((ext_vector_type(4))) float f32x4;

__device__ inline unsigned short rne_bf16(float x){
  union { float f; unsigned u; } c; c.f = x;
  unsigned u = c.u;
  return (unsigned short)((u + 0x7FFFu + ((u>>16)&1u)) >> 16);
}
__device__ inline float bf16f(unsigned short h){
  union { unsigned u; float f; } c; c.u = ((unsigned)h)<<16; return c.f;
}

// ---- pool_w inverse norms ----
__global__ __launch_bounds__(128) void k_wnorm(const float* pw, float* wni){
  int l = blockIdx.x, t = threadIdx.x;
  __shared__ float s[128];
  float v = pw[l*DD + t];
  s[t] = v*v; __syncthreads();
  for (int o=64;o>0;o>>=1){ if (t<o) s[t]+=s[t+o]; __syncthreads(); }
  if (t==0) wni[l] = 1.0f/sqrtf(s[0]);
}

__global__ __launch_bounds__(256) void k_init_ecnt(int* e0){ e0[threadIdx.x] = ECAPG; }

// ---- weight prep: transpose + split to bf16 hi/lo; 15 matrices [128x128] ----
__global__ __launch_bounds__(128) void k_wprep(const float* Wq, const float* Wk, const float* Wv,
                                               const float* Ws, const float* Wt,
                                               unsigned short* whi, unsigned short* wlo){
  int b = blockIdx.x;            // w*128 + krow
  int w = b>>7, krow = b&127, n = threadIdx.x;
  int layer = w/5, which = w - layer*5;
  const float* W = (which==0)?Wq:(which==1)?Wk:(which==2)?Wv:(which==3)?Ws:Wt;
  float v = W[(size_t)layer*DD*DD + krow*DD + n];
  unsigned short h = rne_bf16(v);
  unsigned short l = rne_bf16(v - bf16f(h));
  whi[(size_t)w*DD*DD + (size_t)n*DD + krow] = h;   // transposed: [n][k]
  wlo[(size_t)w*DD*DD + (size_t)n*DD + krow] = l;
}

// ---- X split: fp32 -> bf16 hi/lo global buffers ----
__global__ __launch_bounds__(256) void k_xsplit(const float* __restrict__ X,
                                                unsigned short* __restrict__ xh,
                                                unsigned short* __restrict__ xl, int total4){
  int i = blockIdx.x*256 + threadIdx.x;   // float4 index
  if (i >= total4) return;
  float4 v = ((const float4*)X)[i];
  unsigned short h0=rne_bf16(v.x), h1=rne_bf16(v.y), h2=rne_bf16(v.z), h3=rne_bf16(v.w);
  unsigned short l0=rne_bf16(v.x-bf16f(h0)), l1=rne_bf16(v.y-bf16f(h1)),
                 l2=rne_bf16(v.z-bf16f(h2)), l3=rne_bf16(v.w-bf16f(h3));
  uint2 uh, ul;
  uh.x = (unsigned)h0 | ((unsigned)h1<<16); uh.y = (unsigned)h2 | ((unsigned)h3<<16);
  ul.x = (unsigned)l0 | ((unsigned)l1<<16); ul.y = (unsigned)l2 | ((unsigned)l3<<16);
  ((uint2*)xh)[i] = uh; ((uint2*)xl)[i] = ul;
}

// ---- CSR build, one block per graph, LDS atomics only ----
__global__ __launch_bounds__(256) void k_csr(const int* __restrict__ src, const int* __restrict__ dst,
                                             const int* ecnt, int n,
                                             int* row_start, int* row_end, int* ssrc){
  int g = blockIdx.x, t = threadIdx.x;
  int E = ecnt[g];
  int base = g*ECAPG;
  __shared__ int cnt[256], cur[256], sc[256];
  if (t<256) cnt[t]=0;
  __syncthreads();
  for (int i=t; i<E; i+=256) atomicAdd(&cnt[dst[base+i]-g*n], 1);
  __syncthreads();
  int c = (t<n)?cnt[t]:0;
  sc[t]=c; __syncthreads();
  for (int o=1;o<256;o<<=1){ int add = (t>=o)?sc[t-o]:0; __syncthreads(); sc[t]+=add; __syncthreads(); }
  if (t<n){
    int rs = base + sc[t]-c;
    row_start[g*n+t]=rs; row_end[g*n+t]=rs+c; cur[t]=rs;
  }
  __syncthreads();
  for (int i=t; i<E; i+=256){
    int d = dst[base+i]-g*n;
    int p = atomicAdd(&cur[d],1);
    ssrc[p] = src[base+i];
  }
}

// ---- split-bf16 MFMA GEMM: O = act(X @ W + b); block = 128 rows x 128 cols ----
struct GArgs {
  const unsigned short* whi[4];
  const unsigned short* wlo[4];
  const float* bias[4];
  float* O[4];
};

__global__ __launch_bounds__(256) void k_gemm_mfma(const unsigned short* __restrict__ XHg,
                                                   const unsigned short* __restrict__ XLg,
                                                   GArgs a, int relu){
  __shared__ unsigned short XH[128][40], XL[128][40], WHs[128][40], WLs[128][40];
  int head = blockIdx.y;
  const unsigned short* WH = a.whi[head];
  const unsigned short* WL = a.wlo[head];
  size_t rowBase = (size_t)blockIdx.x*128;
  int t = threadIdx.x;
  int w = t>>6, l = t&63;
  int wr = (w>>1)*64, wc = (w&1)*64;
  int lr = l&15, lk = (l>>4)*8;
  f32x4 acc[4][4] = {};
  for (int kc=0; kc<128; kc+=32){
    __syncthreads();
    for (int i=t; i<1024; i+=256){
      int r = i>>3, c4 = (i&7)*4;
      size_t go = (rowBase + r)*DD + kc + c4;
      *(uint2*)&XH[r][c4] = *(const uint2*)(XHg + go);
      *(uint2*)&XL[r][c4] = *(const uint2*)(XLg + go);
      size_t wo = (size_t)r*DD + kc + c4;
      *(uint2*)&WHs[r][c4] = *(const uint2*)(WH + wo);
      *(uint2*)&WLs[r][c4] = *(const uint2*)(WL + wo);
    }
    __syncthreads();
    bf16x8 ah[4], al[4], bh[4], bl[4];
    #pragma unroll
    for (int m=0;m<4;m++){
      ah[m] = *(bf16x8*)&XH[wr + m*16 + lr][lk];
      al[m] = *(bf16x8*)&XL[wr + m*16 + lr][lk];
    }
    #pragma unroll
    for (int n=0;n<4;n++){
      bh[n] = *(bf16x8*)&WHs[wc + n*16 + lr][lk];
      bl[n] = *(bf16x8*)&WLs[wc + n*16 + lr][lk];
    }
    #pragma unroll
    for (int m=0;m<4;m++){
      #pragma unroll
      for (int n=0;n<4;n++){
        acc[m][n] = __builtin_amdgcn_mfma_f32_16x16x32_bf16(ah[m], bh[n], acc[m][n], 0,0,0);
        acc[m][n] = __builtin_amdgcn_mfma_f32_16x16x32_bf16(ah[m], bl[n], acc[m][n], 0,0,0);
        acc[m][n] = __builtin_amdgcn_mfma_f32_16x16x32_bf16(al[m], bh[n], acc[m][n], 0,0,0);
      }
    }
  }
  float* O = a.O[head];
  const float* bias = a.bias[head];
  #pragma unroll
  for (int n=0;n<4;n++){
    int col = wc + n*16 + lr;
    float bv = bias[col];
    #pragma unroll
    for (int m=0;m<4;m++){
      int rb = wr + m*16 + (l>>4)*4;
      #pragma unroll
      for (int r=0;r<4;r++){
        float o = acc[m][n][r] + bv;
        if (relu) o = fmaxf(o, 0.f);
        O[(rowBase + rb + r)*DD + col] = o;
      }
    }
  }
}

// ---- attention: one wave per dst node ----
__global__ __launch_bounds__(256) void k_attn(const float* __restrict__ q, const float* __restrict__ k,
                                              const float* __restrict__ v,
                                              const int* row_start, const int* row_end,
                                              const int* ssrc, float* xat){
  int w = threadIdx.x >> 6, lane = threadIdx.x & 63;
  int node = blockIdx.x*4 + w;
  __shared__ float lg[4][128];
  const float isd = 0.088388347648318447f;
  float2 qv = *(const float2*)(q + (size_t)node*DD + lane*2);
  int s0 = row_start[node], s1 = row_end[node];
  int deg = s1 - s0; if (deg > 128) deg = 128;
  for (int j=0;j<deg;j++){
    int s = ssrc[s0+j];
    float2 kv = *(const float2*)(k + (size_t)s*DD + lane*2);
    float p = qv.x*kv.x + qv.y*kv.y;
    #pragma unroll
    for (int o=32;o>0;o>>=1) p += __shfl_xor(p, o, 64);
    if (lane==0) lg[w][j] = p * isd;
  }
  __syncthreads();
  float acc0=0.f, acc1=0.f;
  if (deg > 0){
    float m = -1e30f;
    for (int j=0;j<deg;j++) m = fmaxf(m, lg[w][j]);
    float denom = 0.f;
    for (int j=0;j<deg;j++) denom += expf(lg[w][j]-m);
    float rd = 1.0f/denom;
    for (int j=0;j<deg;j++){
      int s = ssrc[s0+j];
      float a = expf(lg[w][j]-m)*rd;
      float2 vv = *(const float2*)(v + (size_t)s*DD + lane*2);
      acc0 += a*vv.x; acc1 += a*vv.y;
    }
  }
  float2 xo = *(const float2*)(xat + (size_t)node*DD + lane*2);
  xo.x += acc0; xo.y += acc1;
  *(float2*)(xat + (size_t)node*DD + lane*2) = xo;
}

// ---- batchnorm stats ----
__global__ __launch_bounds__(256) void k_bnpart(const float* __restrict__ h, float* psum, float* psq, int rpb){
  int c = threadIdx.x & 127, half = threadIdx.x >> 7;
  size_t base = (size_t)blockIdx.x * rpb;
  float s=0.f, s2=0.f;
  for (int r=half; r<rpb; r+=2){
    float x = h[(base+r)*DD + c];
    s += x; s2 += x*x;
  }
  __shared__ float sh[256], sh2[256];
  sh[threadIdx.x]=s; sh2[threadIdx.x]=s2;
  __syncthreads();
  if (half==0){
    psum[blockIdx.x*DD + c] = s + sh[threadIdx.x+128];
    psq [blockIdx.x*DD + c] = s2 + sh2[threadIdx.x+128];
  }
}

__global__ __launch_bounds__(128) void k_bnfin(const float* psum, const float* psq,
                                               float* mu, float* istd, float invN){
  int c = threadIdx.x;
  float s=0.f, s2=0.f;
  for (int b2=0;b2<128;b2++){ s += psum[b2*DD+c]; s2 += psq[b2*DD+c]; }
  float m = s*invN;
  float var = fmaxf(s2*invN - m*m, 0.f);
  mu[c]=m; istd[c] = 1.0f/sqrtf(var + 1e-5f);
}

// ---- BN-normalize + pooling score ----
__global__ __launch_bounds__(256) void k_score(const float* __restrict__ h, const float* mu, const float* istd,
                                               const float* gamma, const float* beta,
                                               const float* pw, const float* wni,
                                               float* xbn, float* score){
  int w = threadIdx.x>>6, lane = threadIdx.x&63;
  int node = blockIdx.x*4 + w;
  int d0 = lane*2;
  float2 hv = *(const float2*)(h + (size_t)node*DD + d0);
  float x0 = (hv.x - mu[d0  ])*istd[d0  ]*gamma[d0  ] + beta[d0  ];
  float x1 = (hv.y - mu[d0+1])*istd[d0+1]*gamma[d0+1] + beta[d0+1];
  *(float2*)(xbn + (size_t)node*DD + d0) = make_float2(x0,x1);
  float p = x0*pw[d0] + x1*pw[d0+1];
  #pragma unroll
  for (int o=32;o>0;o>>=1) p += __shfl_xor(p, o, 64);
  if (lane==0) score[node] = tanhf(p * wni[0]);
}

// ---- per-graph top-k exact ranking ----
__global__ __launch_bounds__(256) void k_topk(const float* score, int n, int kk,
                                              int* sel, float* skeep, int* newid){
  int g = blockIdx.x, t = threadIdx.x;
  __shared__ float ss[256];
  if (t<n) ss[t] = score[g*n+t];
  __syncthreads();
  if (t>=n) return;
  float si = ss[t];
  int rank = 0;
  for (int j=0;j<n;j++){
    float sj = ss[j];
    rank += (sj > si) || ((sj == si) && (j < t));
  }
  if (rank < kk){
    sel[g*kk+rank] = g*n+t;
    skeep[g*kk+rank] = si;
    newid[g*n+t] = g*kk + rank;
  } else {
    newid[g*n+t] = -1;
  }
}

__global__ __launch_bounds__(256) void k_gather(const float* __restrict__ xbn, const int* sel,
                                                const float* skeep, float* xn){
  int w = threadIdx.x>>6, lane = threadIdx.x&63;
  int p = blockIdx.x*4 + w;
  int srow = sel[p]; float sc = skeep[p];
  float2 xv = *(const float2*)(xbn + (size_t)srow*DD + lane*2);
  xv.x *= sc; xv.y *= sc;
  *(float2*)(xn + (size_t)p*DD + lane*2) = xv;
}

__global__ __launch_bounds__(128) void k_readout(const float* __restrict__ xn, float* out, int kk, int layer){
  int g = blockIdx.x, c = threadIdx.x;
  float mx = -1e30f, sm = 0.f;
  for (int nd=0; nd<kk; nd++){
    float x = xn[((size_t)g*kk + nd)*DD + c];
    mx = fmaxf(mx, x); sm += x;
  }
  float* ob = out + (size_t)g*(3*3*DD) + layer*3*DD;
  ob[c] = mx; ob[DD+c] = sm/(float)kk; ob[2*DD+c] = sm;
}

// ---- deterministic per-graph edge compaction (no global atomics) ----
__global__ __launch_bounds__(256) void k_compact(const int* __restrict__ src, const int* __restrict__ dst,
                                                 const int* ecnt, const int* __restrict__ newid,
                                                 int* nsrc, int* ndst, int* necnt){
  int g = blockIdx.x, t = threadIdx.x;
  int E = ecnt[g];
  int base = g*ECAPG;
  __shared__ int sc[256];
  int cntl = 0;
  for (int j=0;j<8;j++){
    int i = t*8+j;
    if (i < E){
      int s_ = newid[src[base+i]], d_ = newid[dst[base+i]];
      if (s_>=0 && d_>=0) cntl++;
    }
  }
  sc[t]=cntl; __syncthreads();
  for (int o=1;o<256;o<<=1){ int add = (t>=o)?sc[t-o]:0; __syncthreads(); sc[t]+=add; __syncthreads(); }
  int off = base + sc[t]-cntl;
  for (int j=0;j<8;j++){
    int i = t*8+j;
    if (i < E){
      int s_ = newid[src[base+i]], d_ = newid[dst[base+i]];
      if (s_>=0 && d_>=0){ nsrc[off]=s_; ndst[off]=d_; off++; }
    }
  }
  if (t==255) necnt[g] = sc[255];
}

extern "C" void kernel_launch(void* const* d_in, const int* in_sizes, int n_in,
                              void* d_out, int out_size, void* d_ws, size_t ws_size,
                              hipStream_t stream){
  const float* x0   = (const float*)d_in[0];
  const int*   eidx = (const int*)d_in[1];
  const float* Wq = (const float*)d_in[4];  const float* bq = (const float*)d_in[5];
  const float* Wk = (const float*)d_in[6];  const float* bk = (const float*)d_in[7];
  const float* Wv = (const float*)d_in[8];  const float* bv = (const float*)d_in[9];
  const float* Wsk= (const float*)d_in[10]; const float* bsk= (const float*)d_in[11];
  const float* Wt = (const float*)d_in[12]; const float* bt = (const float*)d_in[13];
  const float* gamma = (const float*)d_in[14]; const float* beta = (const float*)d_in[15];
  const float* pw = (const float*)d_in[16];

  char* w8 = (char*)d_ws;
  size_t off = 0;
  auto alloc = [&](size_t bytes)->void*{ void* p = w8+off; off += (bytes+255)&~(size_t)255; return p; };

  float* qb  = (float*)alloc((size_t)NMAX*DD*4);
  float* kb  = (float*)alloc((size_t)NMAX*DD*4);
  float* vb  = (float*)alloc((size_t)NMAX*DD*4);
  float* xsb = (float*)alloc((size_t)NMAX*DD*4);
  float* xb0 = (float*)alloc((size_t)(NMAX/2)*DD*4);
  float* xb1 = (float*)alloc((size_t)(NMAX/2)*DD*4);
  unsigned short* xh = (unsigned short*)alloc((size_t)NMAX*DD*2);
  unsigned short* xl = (unsigned short*)alloc((size_t)NMAX*DD*2);
  unsigned short* whi = (unsigned short*)alloc((size_t)15*DD*DD*2);
  unsigned short* wlo = (unsigned short*)alloc((size_t)15*DD*DD*2);
  float* scores = (float*)alloc(NMAX*4);
  float* skeep  = (float*)alloc((NMAX/2)*4);
  float* psum = (float*)alloc(128*DD*4);
  float* psq  = (float*)alloc(128*DD*4);
  float* mu   = (float*)alloc(DD*4);
  float* istd = (float*)alloc(DD*4);
  float* wni  = (float*)alloc(64);
  int* row_start = (int*)alloc(NMAX*4);
  int* row_end   = (int*)alloc(NMAX*4);
  int* ssrc      = (int*)alloc(ETOT*4);
  int* srcA = (int*)alloc(ETOT*4);
  int* dstA = (int*)alloc(ETOT*4);
  int* srcB = (int*)alloc(ETOT*4);
  int* dstB = (int*)alloc(ETOT*4);
  int* sel   = (int*)alloc((NMAX/2)*4);
  int* newid = (int*)alloc(NMAX*4);
  int* ecnt0 = (int*)alloc(NGRAPH*4);
  int* ecntA = (int*)alloc(NGRAPH*4);
  int* ecntB = (int*)alloc(NGRAPH*4);

  k_wnorm<<<3,128,0,stream>>>(pw, wni);
  k_init_ecnt<<<1,256,0,stream>>>(ecnt0);
  k_wprep<<<15*128,128,0,stream>>>(Wq, Wk, Wv, Wsk, Wt, whi, wlo);

  const float* xcur = x0;
  const int* csrc = eidx;
  const int* cdst = eidx + ETOT;
  const int* cecnt = ecnt0;
  int n = 256;

  for (int layer=0; layer<3; layer++){
    int Nn = NGRAPH * n;
    int kk = n/2;

    k_csr<<<NGRAPH,256,0,stream>>>(csrc, cdst, cecnt, n, row_start, row_end, ssrc);

    // X -> bf16 hi/lo
    k_xsplit<<<Nn/8,256,0,stream>>>(xcur, xh, xl, Nn*32);

    GArgs h4;
    h4.whi[0]=whi+(size_t)(layer*5+0)*DD*DD; h4.wlo[0]=wlo+(size_t)(layer*5+0)*DD*DD; h4.bias[0]=bq +layer*DD; h4.O[0]=qb;
    h4.whi[1]=whi+(size_t)(layer*5+1)*DD*DD; h4.wlo[1]=wlo+(size_t)(layer*5+1)*DD*DD; h4.bias[1]=bk +layer*DD; h4.O[1]=kb;
    h4.whi[2]=whi+(size_t)(layer*5+2)*DD*DD; h4.wlo[2]=wlo+(size_t)(layer*5+2)*DD*DD; h4.bias[2]=bv +layer*DD; h4.O[2]=vb;
    h4.whi[3]=whi+(size_t)(layer*5+3)*DD*DD; h4.wlo[3]=wlo+(size_t)(layer*5+3)*DD*DD; h4.bias[3]=bsk+layer*DD; h4.O[3]=xsb;
    k_gemm_mfma<<<dim3(Nn/128,4),256,0,stream>>>(xh, xl, h4, 0);

    k_attn<<<Nn/4,256,0,stream>>>(qb, kb, vb, row_start, row_end, ssrc, xsb);

    // x -> bf16 hi/lo for the transform GEMM
    k_xsplit<<<Nn/8,256,0,stream>>>(xsb, xh, xl, Nn*32);

    GArgs h1;
    h1.whi[0]=whi+(size_t)(layer*5+4)*DD*DD; h1.wlo[0]=wlo+(size_t)(layer*5+4)*DD*DD; h1.bias[0]=bt+layer*DD; h1.O[0]=qb;
    h1.whi[1]=h1.whi[0]; h1.wlo[1]=h1.wlo[0]; h1.bias[1]=h1.bias[0]; h1.O[1]=qb;
    h1.whi[2]=h1.whi[0]; h1.wlo[2]=h1.wlo[0]; h1.bias[2]=h1.bias[0]; h1.O[2]=qb;
    h1.whi[3]=h1.whi[0]; h1.wlo[3]=h1.wlo[0]; h1.bias[3]=h1.bias[0]; h1.O[3]=qb;
    k_gemm_mfma<<<dim3(Nn/128,1),256,0,stream>>>(xh, xl, h1, 1);

    k_bnpart<<<128,256,0,stream>>>(qb, psum, psq, Nn/128);
    k_bnfin <<<1,128,0,stream>>>(psum, psq, mu, istd, 1.0f/(float)Nn);

    k_score<<<Nn/4,256,0,stream>>>(qb, mu, istd, gamma+layer*DD, beta+layer*DD,
                                   pw+layer*DD, wni+layer, kb, scores);

    k_topk<<<NGRAPH,256,0,stream>>>(scores, n, kk, sel, skeep, newid);

    float* xn = (layer==0) ? xb0 : ((layer==1) ? xb1 : xb0);
    k_gather<<<(NGRAPH*kk)/4,256,0,stream>>>(kb, sel, skeep, xn);
    k_readout<<<NGRAPH,128,0,stream>>>(xn, (float*)d_out, kk, layer);

    if (layer<2){
      int* nsrc  = (layer==0) ? srcA : srcB;
      int* ndst  = (layer==0) ? dstA : dstB;
      int* necnt = (layer==0) ? ecntA : ecntB;
      k_compact<<<NGRAPH,256,0,stream>>>(csrc, cdst, cecnt, newid, nsrc, ndst, necnt);
      csrc = nsrc; cdst = ndst; cecnt = necnt;
    }
    xcur = xn; n = kk;
  }
}

// Round 4
// 571.995 us; speedup vs baseline: 3.1287x; 1.2298x over previous
//
#include <hip/hip_runtime.h>
#include <hip/hip_bf16.h>
#include <math.h>

// B=256 graphs, N=256 nodes/graph, DEG=8, D=128, L=3.
#define DD     128
#define NGRAPH 256
#define ECAPG  2048
#define ETOT   (NGRAPH*ECAPG)
#define NMAX   65536

typedef __attribute__((ext_vector_type(8))) short bf16x8;
typedef __attribute__((ext_vector_type(4))) float f32x4;

__device__ inline unsigned short rne_bf16(float x){
  union { float f; unsigned u; } c; c.f = x;
  unsigned u = c.u;
  return (unsigned short)((u + 0x7FFFu + ((u>>16)&1u)) >> 16);
}
__device__ inline float bf16f(unsigned short h){
  union { unsigned u; float f; } c; c.u = ((unsigned)h)<<16; return c.f;
}

// ---- pool_w inverse norms ----
__global__ __launch_bounds__(128) void k_wnorm(const float* pw, float* wni){
  int l = blockIdx.x, t = threadIdx.x;
  __shared__ float s[128];
  float v = pw[l*DD + t];
  s[t] = v*v; __syncthreads();
  for (int o=64;o>0;o>>=1){ if (t<o) s[t]+=s[t+o]; __syncthreads(); }
  if (t==0) wni[l] = 1.0f/sqrtf(s[0]);
}

// ---- weight prep: transpose + split to bf16 hi/lo; 15 matrices [128x128] ----
__global__ __launch_bounds__(128) void k_wprep(const float* Wq, const float* Wk, const float* Wv,
                                               const float* Ws, const float* Wt,
                                               unsigned short* whi, unsigned short* wlo){
  int b = blockIdx.x;            // w*128 + krow
  int w = b>>7, krow = b&127, n = threadIdx.x;
  int layer = w/5, which = w - layer*5;
  const float* W = (which==0)?Wq:(which==1)?Wk:(which==2)?Wv:(which==3)?Ws:Wt;
  float v = W[(size_t)layer*DD*DD + krow*DD + n];
  unsigned short h = rne_bf16(v);
  unsigned short l = rne_bf16(v - bf16f(h));
  whi[(size_t)w*DD*DD + (size_t)n*DD + krow] = h;   // transposed: [n][k]
  wlo[(size_t)w*DD*DD + (size_t)n*DD + krow] = l;
}

// ---- X split: fp32 -> bf16 hi/lo (initial x0 only) ----
__global__ __launch_bounds__(256) void k_xsplit(const float* __restrict__ X,
                                                unsigned short* __restrict__ xh,
                                                unsigned short* __restrict__ xl, int total4){
  int i = blockIdx.x*256 + threadIdx.x;
  if (i >= total4) return;
  float4 v = ((const float4*)X)[i];
  unsigned short h0=rne_bf16(v.x), h1=rne_bf16(v.y), h2=rne_bf16(v.z), h3=rne_bf16(v.w);
  unsigned short l0=rne_bf16(v.x-bf16f(h0)), l1=rne_bf16(v.y-bf16f(h1)),
                 l2=rne_bf16(v.z-bf16f(h2)), l3=rne_bf16(v.w-bf16f(h3));
  uint2 uh, ul;
  uh.x = (unsigned)h0 | ((unsigned)h1<<16); uh.y = (unsigned)h2 | ((unsigned)h3<<16);
  ul.x = (unsigned)l0 | ((unsigned)l1<<16); ul.y = (unsigned)l2 | ((unsigned)l3<<16);
  ((uint2*)xh)[i] = uh; ((uint2*)xl)[i] = ul;
}

// ---- CSR build (layer 0 only), one block per graph, LDS atomics only ----
__global__ __launch_bounds__(256) void k_csr(const int* __restrict__ src, const int* __restrict__ dst,
                                             const int* ecnt, int n,
                                             int* row_start, int* row_end, int* ssrc){
  int g = blockIdx.x, t = threadIdx.x;
  int E = ecnt ? ecnt[g] : ECAPG;
  int base = g*ECAPG;
  __shared__ int cnt[256], cur[256], sc[256];
  cnt[t]=0;
  __syncthreads();
  for (int i=t; i<E; i+=256) atomicAdd(&cnt[dst[base+i]-g*n], 1);
  __syncthreads();
  int c = (t<n)?cnt[t]:0;
  sc[t]=c; __syncthreads();
  for (int o=1;o<256;o<<=1){ int add = (t>=o)?sc[t-o]:0; __syncthreads(); sc[t]+=add; __syncthreads(); }
  if (t<n){
    int rs = base + sc[t]-c;
    row_start[g*n+t]=rs; row_end[g*n+t]=rs+c; cur[t]=rs;
  }
  __syncthreads();
  for (int i=t; i<E; i+=256){
    int d = dst[base+i]-g*n;
    int p = atomicAdd(&cur[d],1);
    ssrc[p] = src[base+i];
  }
}

// ---- split-bf16 MFMA GEMM: O = act(X @ W + b); block = 128 rows x 128 cols ----
// BN=1: relu + per-block column sum / sum-of-squares partials (deterministic).
struct GArgs {
  const unsigned short* whi[4];
  const unsigned short* wlo[4];
  const float* bias[4];
  float*       O[4];
};

template<int BN>
__global__ __launch_bounds__(256) void k_gemm_mfma(const unsigned short* __restrict__ XHg,
                                                   const unsigned short* __restrict__ XLg,
                                                   GArgs a, float* __restrict__ psum,
                                                   float* __restrict__ psq){
  __shared__ unsigned short XH[128][40], XL[128][40], WHs[128][40], WLs[128][40];
  int head = BN ? 0 : blockIdx.y;
  const unsigned short* WH = a.whi[head];
  const unsigned short* WL = a.wlo[head];
  size_t rowBase = (size_t)blockIdx.x*128;
  int t = threadIdx.x;
  int w = t>>6, l = t&63;
  int wr = (w>>1)*64, wc = (w&1)*64;
  int lr = l&15, lk = (l>>4)*8;
  f32x4 acc[4][4] = {};
  for (int kc=0; kc<128; kc+=32){
    __syncthreads();
    for (int i=t; i<1024; i+=256){
      int r = i>>3, c4 = (i&7)*4;
      size_t go = (rowBase + r)*DD + kc + c4;
      *(uint2*)&XH[r][c4] = *(const uint2*)(XHg + go);
      *(uint2*)&XL[r][c4] = *(const uint2*)(XLg + go);
      size_t wo = (size_t)r*DD + kc + c4;
      *(uint2*)&WHs[r][c4] = *(const uint2*)(WH + wo);
      *(uint2*)&WLs[r][c4] = *(const uint2*)(WL + wo);
    }
    __syncthreads();
    bf16x8 ah[4], al[4], bh[4], bl[4];
    #pragma unroll
    for (int m=0;m<4;m++){
      ah[m] = *(bf16x8*)&XH[wr + m*16 + lr][lk];
      al[m] = *(bf16x8*)&XL[wr + m*16 + lr][lk];
    }
    #pragma unroll
    for (int n=0;n<4;n++){
      bh[n] = *(bf16x8*)&WHs[wc + n*16 + lr][lk];
      bl[n] = *(bf16x8*)&WLs[wc + n*16 + lr][lk];
    }
    #pragma unroll
    for (int m=0;m<4;m++){
      #pragma unroll
      for (int n=0;n<4;n++){
        acc[m][n] = __builtin_amdgcn_mfma_f32_16x16x32_bf16(ah[m], bh[n], acc[m][n], 0,0,0);
        acc[m][n] = __builtin_amdgcn_mfma_f32_16x16x32_bf16(ah[m], bl[n], acc[m][n], 0,0,0);
        acc[m][n] = __builtin_amdgcn_mfma_f32_16x16x32_bf16(al[m], bh[n], acc[m][n], 0,0,0);
      }
    }
  }
  float* O = a.O[head];
  const float* bias = a.bias[head];
  float cs[4] = {0.f,0.f,0.f,0.f}, cq[4] = {0.f,0.f,0.f,0.f};
  #pragma unroll
  for (int n=0;n<4;n++){
    int col = wc + n*16 + lr;
    float bv = bias[col];
    #pragma unroll
    for (int m=0;m<4;m++){
      int rb = wr + m*16 + (l>>4)*4;
      #pragma unroll
      for (int r=0;r<4;r++){
        float o = acc[m][n][r] + bv;
        if (BN) o = fmaxf(o, 0.f);
        O[(rowBase + rb + r)*DD + col] = o;
        if (BN){ cs[n] += o; cq[n] += o*o; }
      }
    }
  }
  if (BN){
    __syncthreads();                       // all LDS tile reads done
    float* redS = (float*)&XH[0][0];       // 16*132 floats = 8448B <= 10240B
    float* redQ = (float*)&XL[0][0];
    int rg = w*4 + (l>>4);
    #pragma unroll
    for (int n=0;n<4;n++){
      int col = wc + n*16 + lr;
      redS[rg*132 + col] = cs[n];
      redQ[rg*132 + col] = cq[n];
    }
    __syncthreads();
    if (t < 128){
      int c = t, w0 = (c>=64) ? 1 : 0;
      float s = 0.f, s2 = 0.f;
      #pragma unroll
      for (int dw=0; dw<2; dw++){
        int ww = w0 + dw*2;
        #pragma unroll
        for (int lq=0; lq<4; lq++){
          s  += redS[(ww*4+lq)*132 + c];
          s2 += redQ[(ww*4+lq)*132 + c];
        }
      }
      psum[blockIdx.x*DD + c] = s;
      psq [blockIdx.x*DD + c] = s2;
    }
  }
}

// ---- parallel-edge attention (exact fp32) + skip add + bf16 hi/lo split ----
// 1 wave per dst node; 8 groups of 8 lanes process 8 edges concurrently.
__global__ __launch_bounds__(256) void k_attn_par(
    const float* __restrict__ q, const float* __restrict__ k, const float* __restrict__ v,
    const int* __restrict__ row_start, const int* __restrict__ row_end,
    const int* __restrict__ ssrc, const float* __restrict__ skip,
    unsigned short* __restrict__ xh, unsigned short* __restrict__ xl)
{
  __shared__ float lg[4][128];
  // XCD swizzle: consecutive logical blocks (same graph) land on the same XCD.
  int nb8 = gridDim.x >> 3;
  int p = blockIdx.x;
  int lb = (p&7)*nb8 + (p>>3);
  int w = threadIdx.x>>6, l = threadIdx.x&63;
  int node = lb*4 + w;
  size_t nb = (size_t)node*DD;
  int s0 = row_start[node], deg = row_end[node]-s0; if (deg>128) deg=128;
  int h8 = l>>3, gl = l&7;
  float4 qv0 = *(const float4*)(q + nb + gl*16);
  float4 qv1 = *(const float4*)(q + nb + gl*16 + 4);
  float4 qv2 = *(const float4*)(q + nb + gl*16 + 8);
  float4 qv3 = *(const float4*)(q + nb + gl*16 + 12);
  const float isd = 0.088388347648318447f;  // 1/sqrt(128)
  for (int base=0; base<deg; base+=8){
    int e = base + h8;
    int s = ssrc[s0 + (e<deg ? e : 0)];
    const float* kp = k + (size_t)s*DD + gl*16;
    float4 k0=*(const float4*)kp, k1=*(const float4*)(kp+4),
           k2=*(const float4*)(kp+8), k3=*(const float4*)(kp+12);
    float pd = qv0.x*k0.x+qv0.y*k0.y+qv0.z*k0.z+qv0.w*k0.w
             + qv1.x*k1.x+qv1.y*k1.y+qv1.z*k1.z+qv1.w*k1.w
             + qv2.x*k2.x+qv2.y*k2.y+qv2.z*k2.z+qv2.w*k2.w
             + qv3.x*k3.x+qv3.y*k3.y+qv3.z*k3.z+qv3.w*k3.w;
    pd += __shfl_xor(pd,1,64); pd += __shfl_xor(pd,2,64); pd += __shfl_xor(pd,4,64);
    if (gl==0 && e<deg) lg[w][e] = pd*isd;
  }
  float v1 = (l    <deg) ? lg[w][l]    : -1e30f;
  float v2 = (64+l <deg) ? lg[w][64+l] : -1e30f;
  float m = fmaxf(v1,v2);
  #pragma unroll
  for (int o=32;o>0;o>>=1) m = fmaxf(m, __shfl_xor(m,o,64));
  float e1 = (l   <deg) ? expf(v1-m) : 0.f;
  float e2 = (64+l<deg) ? expf(v2-m) : 0.f;
  float dn = e1+e2;
  #pragma unroll
  for (int o=32;o>0;o>>=1) dn += __shfl_xor(dn,o,64);
  float rd = 1.0f/fmaxf(dn, 1e-16f);
  if (l   <deg) lg[w][l]    = e1*rd;
  if (64+l<deg) lg[w][64+l] = e2*rd;
  float a0=0.f, a1=0.f;
  for (int e=0;e<deg;e++){
    int s = ssrc[s0+e];
    float al = lg[w][e];
    float2 vv = *(const float2*)(v + (size_t)s*DD + l*2);
    a0 += al*vv.x; a1 += al*vv.y;
  }
  float2 sk = *(const float2*)(skip + nb + l*2);
  float x0 = sk.x + a0, x1 = sk.y + a1;
  unsigned short h0=rne_bf16(x0), h1=rne_bf16(x1);
  unsigned short l0=rne_bf16(x0-bf16f(h0)), l1=rne_bf16(x1-bf16f(h1));
  *(unsigned*)(xh + nb + l*2) = (unsigned)h0 | ((unsigned)h1<<16);
  *(unsigned*)(xl + nb + l*2) = (unsigned)l0 | ((unsigned)l1<<16);
}

// ---- BN final: reduce per-block partials ----
__global__ __launch_bounds__(128) void k_bnfin(const float* psum, const float* psq,
                                               float* mu, float* istd, float invN, int nblk){
  int c = threadIdx.x;
  float s=0.f, s2=0.f;
  for (int b=0;b<nblk;b++){ s += psum[b*DD+c]; s2 += psq[b*DD+c]; }
  float m = s*invN;
  float var = fmaxf(s2*invN - m*m, 0.f);
  mu[c]=m; istd[c] = 1.0f/sqrtf(var + 1e-5f);
}

// ---- fused per-graph: BN-score + topk + gather/scale/split + readout + compact + next CSR ----
__global__ __launch_bounds__(256) void k_pool(
    const float* __restrict__ h, const float* __restrict__ mu, const float* __restrict__ istd,
    const float* __restrict__ gma, const float* __restrict__ bta,
    const float* __restrict__ pw, const float* __restrict__ wni, int layer, int n,
    const int* __restrict__ osrc, const int* __restrict__ odst, const int* __restrict__ oecnt,
    unsigned short* __restrict__ xh, unsigned short* __restrict__ xl,
    float* __restrict__ out,
    int* __restrict__ nsrc, int* __restrict__ ndst, int* __restrict__ necnt,
    int* __restrict__ row_start, int* __restrict__ row_end, int* __restrict__ ssrc, int do_edges)
{
  int g = blockIdx.x, t = threadIdx.x;
  int kk = n>>1;
  __shared__ float bnp[5][128];
  __shared__ float ss[256];
  __shared__ int   sel[128];
  __shared__ float skp[128];
  __shared__ int   nid[256];
  __shared__ float redm[4][128], rdsum[4][128];
  __shared__ int   esrc[ECAPG], edst[ECAPG];
  __shared__ int   sc[256];
  __shared__ int   cnt[128], cur[128];

  if (t<128){ bnp[0][t]=mu[t]; bnp[1][t]=istd[t]; bnp[2][t]=gma[t]; bnp[3][t]=bta[t]; bnp[4][t]=pw[t]; }
  __syncthreads();
  // A: pooling scores
  if (t<n){
    const float* hr = h + ((size_t)g*n + t)*DD;
    float dot = 0.f;
    for (int c=0;c<DD;c+=4){
      float4 hv = *(const float4*)(hr+c);
      dot += ((hv.x-bnp[0][c+0])*bnp[1][c+0]*bnp[2][c+0]+bnp[3][c+0])*bnp[4][c+0];
      dot += ((hv.y-bnp[0][c+1])*bnp[1][c+1]*bnp[2][c+1]+bnp[3][c+1])*bnp[4][c+1];
      dot += ((hv.z-bnp[0][c+2])*bnp[1][c+2]*bnp[2][c+2]+bnp[3][c+2])*bnp[4][c+2];
      dot += ((hv.w-bnp[0][c+3])*bnp[1][c+3]*bnp[2][c+3]+bnp[3][c+3])*bnp[4][c+3];
    }
    ss[t] = tanhf(dot * wni[0]);
  }
  __syncthreads();
  // B: top-k exact ranking (matches jax.lax.top_k tie order)
  if (t<n){
    float si = ss[t]; int rank = 0;
    for (int j=0;j<n;j++){ float sj = ss[j]; rank += (sj>si)||((sj==si)&&(j<t)); }
    if (rank<kk){ sel[rank]=t; skp[rank]=si; nid[t]=g*kk+rank; } else nid[t]=-1;
  }
  __syncthreads();
  // C: gather + BN + scale + bf16 split + readout partials
  int w = t>>6, l = t&63, d0 = l*2;
  float m0=-1e30f, m1=-1e30f, sm0=0.f, sm1=0.f;
  for (int p=w; p<kk; p+=4){
    int srow = sel[p]; float scv = skp[p];
    float2 hv = *(const float2*)(h + ((size_t)g*n + srow)*DD + d0);
    float x0 = ((hv.x-bnp[0][d0  ])*bnp[1][d0  ]*bnp[2][d0  ]+bnp[3][d0  ])*scv;
    float x1 = ((hv.y-bnp[0][d0+1])*bnp[1][d0+1]*bnp[2][d0+1]+bnp[3][d0+1])*scv;
    m0 = fmaxf(m0,x0); m1 = fmaxf(m1,x1); sm0 += x0; sm1 += x1;
    unsigned short h0=rne_bf16(x0), h1=rne_bf16(x1);
    unsigned short l0=rne_bf16(x0-bf16f(h0)), l1=rne_bf16(x1-bf16f(h1));
    size_t ob = ((size_t)g*kk + p)*DD + d0;
    *(unsigned*)(xh+ob) = (unsigned)h0 | ((unsigned)h1<<16);
    *(unsigned*)(xl+ob) = (unsigned)l0 | ((unsigned)l1<<16);
  }
  redm[w][d0]=m0; redm[w][d0+1]=m1; rdsum[w][d0]=sm0; rdsum[w][d0+1]=sm1;
  __syncthreads();
  if (t<128){
    float mx = fmaxf(fmaxf(redm[0][t],redm[1][t]), fmaxf(redm[2][t],redm[3][t]));
    float sm = rdsum[0][t]+rdsum[1][t]+rdsum[2][t]+rdsum[3][t];
    float* ob = out + (size_t)g*1152 + layer*384;
    ob[t]=mx; ob[128+t]=sm/(float)kk; ob[256+t]=sm;
  }
  if (!do_edges) return;
  // D: edge compaction (deterministic scan) + next-layer CSR
  int E = oecnt ? oecnt[g] : ECAPG;
  int base = g*ECAPG;
  int cl = 0;
  for (int j=0;j<8;j++){ int i=t*8+j;
    if (i<E){ int ns=nid[osrc[base+i]-g*n], nd=nid[odst[base+i]-g*n]; if ((ns|nd)>=0) cl++; } }
  sc[t]=cl; __syncthreads();
  for (int o=1;o<256;o<<=1){ int add=(t>=o)?sc[t-o]:0; __syncthreads(); sc[t]+=add; __syncthreads(); }
  int off = sc[t]-cl;
  for (int j=0;j<8;j++){ int i=t*8+j;
    if (i<E){ int ns=nid[osrc[base+i]-g*n], nd=nid[odst[base+i]-g*n];
      if ((ns|nd)>=0){ esrc[off]=ns; edst[off]=nd-g*kk; off++; } } }
  int Etot = sc[255];
  __syncthreads();
  if (t==0) necnt[g]=Etot;
  for (int i=t;i<Etot;i+=256){ nsrc[base+i]=esrc[i]; ndst[base+i]=edst[i]+g*kk; }
  if (t<128) cnt[t]=0;
  __syncthreads();
  for (int i=t;i<Etot;i+=256) atomicAdd(&cnt[edst[i]],1);
  __syncthreads();
  int c2 = (t<kk)?cnt[t]:0;
  sc[t]=c2; __syncthreads();
  for (int o=1;o<256;o<<=1){ int add=(t>=o)?sc[t-o]:0; __syncthreads(); sc[t]+=add; __syncthreads(); }
  if (t<kk){ int rs=base+sc[t]-c2; row_start[g*kk+t]=rs; row_end[g*kk+t]=rs+c2; cur[t]=rs; }
  __syncthreads();
  for (int i=t;i<Etot;i+=256){ int p2=atomicAdd(&cur[edst[i]],1); ssrc[p2]=esrc[i]; }
}

extern "C" void kernel_launch(void* const* d_in, const int* in_sizes, int n_in,
                              void* d_out, int out_size, void* d_ws, size_t ws_size,
                              hipStream_t stream){
  const float* x0   = (const float*)d_in[0];
  const int*   eidx = (const int*)d_in[1];
  const float* Wq = (const float*)d_in[4];  const float* bq = (const float*)d_in[5];
  const float* Wk = (const float*)d_in[6];  const float* bk = (const float*)d_in[7];
  const float* Wv = (const float*)d_in[8];  const float* bv = (const float*)d_in[9];
  const float* Wsk= (const float*)d_in[10]; const float* bsk= (const float*)d_in[11];
  const float* Wt = (const float*)d_in[12]; const float* bt = (const float*)d_in[13];
  const float* gamma = (const float*)d_in[14]; const float* beta = (const float*)d_in[15];
  const float* pw = (const float*)d_in[16];

  char* w8 = (char*)d_ws;
  size_t off = 0;
  auto alloc = [&](size_t bytes)->void*{ void* p = w8+off; off += (bytes+255)&~(size_t)255; return p; };

  float* qb  = (float*)alloc((size_t)NMAX*DD*4);   // q, then transform output h
  float* kb  = (float*)alloc((size_t)NMAX*DD*4);
  float* vb  = (float*)alloc((size_t)NMAX*DD*4);
  float* xsb = (float*)alloc((size_t)NMAX*DD*4);   // skip
  unsigned short* xh = (unsigned short*)alloc((size_t)NMAX*DD*2);
  unsigned short* xl = (unsigned short*)alloc((size_t)NMAX*DD*2);
  unsigned short* whi = (unsigned short*)alloc((size_t)15*DD*DD*2);
  unsigned short* wlo = (unsigned short*)alloc((size_t)15*DD*DD*2);
  float* psum = (float*)alloc((size_t)512*DD*4);
  float* psq  = (float*)alloc((size_t)512*DD*4);
  float* mu   = (float*)alloc(DD*4);
  float* istd = (float*)alloc(DD*4);
  float* wni  = (float*)alloc(64);
  int* row_start = (int*)alloc(NMAX*4);
  int* row_end   = (int*)alloc(NMAX*4);
  int* ssrc      = (int*)alloc(ETOT*4);
  int* srcA = (int*)alloc(ETOT*4);
  int* dstA = (int*)alloc(ETOT*4);
  int* srcB = (int*)alloc(ETOT*4);
  int* dstB = (int*)alloc(ETOT*4);
  int* ecntA = (int*)alloc(NGRAPH*4);
  int* ecntB = (int*)alloc(NGRAPH*4);

  k_wnorm<<<3,128,0,stream>>>(pw, wni);
  k_wprep<<<15*128,128,0,stream>>>(Wq, Wk, Wv, Wsk, Wt, whi, wlo);
  k_xsplit<<<NMAX/8,256,0,stream>>>(x0, xh, xl, NMAX*32);
  k_csr<<<NGRAPH,256,0,stream>>>(eidx, eidx+ETOT, nullptr, 256, row_start, row_end, ssrc);

  const int* csrc = eidx;
  const int* cdst = eidx + ETOT;
  const int* cecnt = nullptr;
  int n = 256;

  for (int layer=0; layer<3; layer++){
    int Nn = NGRAPH * n;
    int kk = n/2;

    GArgs h4;
    h4.whi[0]=whi+(size_t)(layer*5+0)*DD*DD; h4.wlo[0]=wlo+(size_t)(layer*5+0)*DD*DD; h4.bias[0]=bq +layer*DD; h4.O[0]=qb;
    h4.whi[1]=whi+(size_t)(layer*5+1)*DD*DD; h4.wlo[1]=wlo+(size_t)(layer*5+1)*DD*DD; h4.bias[1]=bk +layer*DD; h4.O[1]=kb;
    h4.whi[2]=whi+(size_t)(layer*5+2)*DD*DD; h4.wlo[2]=wlo+(size_t)(layer*5+2)*DD*DD; h4.bias[2]=bv +layer*DD; h4.O[2]=vb;
    h4.whi[3]=whi+(size_t)(layer*5+3)*DD*DD; h4.wlo[3]=wlo+(size_t)(layer*5+3)*DD*DD; h4.bias[3]=bsk+layer*DD; h4.O[3]=xsb;
    k_gemm_mfma<0><<<dim3(Nn/128,4),256,0,stream>>>(xh, xl, h4, nullptr, nullptr);

    k_attn_par<<<Nn/4,256,0,stream>>>(qb, kb, vb, row_start, row_end, ssrc, xsb, xh, xl);

    GArgs h1;
    h1.whi[0]=whi+(size_t)(layer*5+4)*DD*DD; h1.wlo[0]=wlo+(size_t)(layer*5+4)*DD*DD; h1.bias[0]=bt+layer*DD; h1.O[0]=qb;
    h1.whi[1]=h1.whi[0]; h1.wlo[1]=h1.wlo[0]; h1.bias[1]=h1.bias[0]; h1.O[1]=qb;
    h1.whi[2]=h1.whi[0]; h1.wlo[2]=h1.wlo[0]; h1.bias[2]=h1.bias[0]; h1.O[2]=qb;
    h1.whi[3]=h1.whi[0]; h1.wlo[3]=h1.wlo[0]; h1.bias[3]=h1.bias[0]; h1.O[3]=qb;
    k_gemm_mfma<1><<<dim3(Nn/128,1),256,0,stream>>>(xh, xl, h1, psum, psq);

    k_bnfin<<<1,128,0,stream>>>(psum, psq, mu, istd, 1.0f/(float)Nn, Nn/128);

    int* nsrc  = (layer==0) ? srcA : srcB;
    int* ndst  = (layer==0) ? dstA : dstB;
    int* necnt = (layer==0) ? ecntA : ecntB;
    k_pool<<<NGRAPH,256,0,stream>>>(qb, mu, istd, gamma+layer*DD, beta+layer*DD,
                                    pw+layer*DD, wni+layer, layer, n,
                                    csrc, cdst, cecnt, xh, xl, (float*)d_out,
                                    nsrc, ndst, necnt, row_start, row_end, ssrc, layer<2 ? 1 : 0);

    csrc = nsrc; cdst = ndst; cecnt = necnt;
    n = kk;
  }
}